// Round 2
// baseline (192.475 us; speedup 1.0000x reference)
//
#include <hip/hip_runtime.h>
#include <math.h>

#define NE 8
#define DD 1024
#define HH 2048
#define NTOK 1024
#define NSLOT 2048
#define NSLOTP 3072

typedef short short8v __attribute__((ext_vector_type(8)));
typedef short short4v __attribute__((ext_vector_type(4)));
typedef float f32x4 __attribute__((ext_vector_type(4)));

static __device__ __forceinline__ unsigned short f2bf(float f) {
  unsigned int x = __float_as_uint(f);
  return (unsigned short)((x + 0x7fffu + ((x >> 16) & 1u)) >> 16);
}

// async global->LDS, 16B per lane; LDS dst must be wave-uniform.
#define GLD16(SRC, DST)                                                        \
  __builtin_amdgcn_global_load_lds(                                            \
      (__attribute__((address_space(1))) void*)(SRC),                          \
      (__attribute__((address_space(3))) void*)(DST), 16, 0, 0)

// ---------------------------------------------------------------------------
// Transpose + f32->bf16: in f32 [R][C] per expert -> out bf16 [C][R].
// Within each 128B block of an output row r, granule g stored at g ^ (r&7)
// so later linear global_load_lds staging + swizzled ds_read is conflict-free.
// ---------------------------------------------------------------------------
__global__ __launch_bounds__(256) void ktranspose(const float* __restrict__ in,
                                                  unsigned short* __restrict__ out,
                                                  int R, int C) {
  __shared__ unsigned short tl[64][72];
  int e = blockIdx.z;
  int r0 = blockIdx.y * 64;
  int c0 = blockIdx.x * 64;
  const float* ein = in + (size_t)e * R * C;
  char* eout = (char*)(out + (size_t)e * C * R);
  int tid = threadIdx.x;
#pragma unroll
  for (int p = 0; p < 4; ++p) {
    int row = p * 16 + (tid >> 4);
    int c4 = (tid & 15) * 4;
    float4 v = *(const float4*)(ein + (size_t)(r0 + row) * C + c0 + c4);
    tl[row][c4 + 0] = f2bf(v.x);
    tl[row][c4 + 1] = f2bf(v.y);
    tl[row][c4 + 2] = f2bf(v.z);
    tl[row][c4 + 3] = f2bf(v.w);
  }
  __syncthreads();
#pragma unroll
  for (int q = 0; q < 2; ++q) {
    int c = q * 32 + (tid >> 3);
    int seg = tid & 7;
    short8v ov;
#pragma unroll
    for (int j = 0; j < 8; ++j) ov[j] = (short)tl[seg * 8 + j][c];
    int cg = c0 + c;
    int s = seg ^ (cg & 7);
    *(short8v*)(eout + (size_t)cg * (R * 2) + (size_t)r0 * 2 + (s << 4)) = ov;
  }
}

// ---------------------------------------------------------------------------
// Router: one wave per token, exact f32, softmax over 8, top-2.
// ---------------------------------------------------------------------------
__global__ __launch_bounds__(64) void krouter(const float* __restrict__ x,
                                              const float* __restrict__ gw,
                                              int* __restrict__ e_sel,
                                              float* __restrict__ w_sel) {
  int n = blockIdx.x;
  int lane = threadIdx.x;
  const float4* xr = (const float4*)(x + (size_t)n * DD);
  const float4* gr = (const float4*)gw;
  float acc[NE];
#pragma unroll
  for (int e = 0; e < NE; ++e) acc[e] = 0.f;
#pragma unroll
  for (int i = 0; i < 4; ++i) {
    float4 xv = xr[lane + i * 64];
#pragma unroll
    for (int e = 0; e < NE; ++e) {
      float4 gv = gr[e * 256 + lane + i * 64];
      acc[e] += xv.x * gv.x + xv.y * gv.y + xv.z * gv.z + xv.w * gv.w;
    }
  }
#pragma unroll
  for (int e = 0; e < NE; ++e)
#pragma unroll
    for (int off = 32; off > 0; off >>= 1) acc[e] += __shfl_xor(acc[e], off);
  if (lane == 0) {
    float m = acc[0];
#pragma unroll
    for (int e = 1; e < NE; ++e) m = fmaxf(m, acc[e]);
    float p[NE];
    float z = 0.f;
#pragma unroll
    for (int e = 0; e < NE; ++e) { p[e] = expf(acc[e] - m); z += p[e]; }
    float inv = 1.f / z;
    int e1 = 0;
#pragma unroll
    for (int e = 1; e < NE; ++e) if (acc[e] > acc[e1]) e1 = e;
    int e2 = (e1 == 0) ? 1 : 0;
#pragma unroll
    for (int e = 0; e < NE; ++e) if (e != e1 && acc[e] > acc[e2]) e2 = e;
    e_sel[n] = e1;         w_sel[n] = p[e1] * inv;
    e_sel[NTOK + n] = e2;  w_sel[NTOK + n] = p[e2] * inv;
  }
}

// ---------------------------------------------------------------------------
// Build per-expert token lists, segments padded to multiples of 128.
// tok[] init to -1 so padded rows are identifiable.
// ---------------------------------------------------------------------------
__global__ __launch_bounds__(256) void kbuild(const int* __restrict__ e_sel,
                                              const float* __restrict__ w_sel,
                                              int* __restrict__ tok,
                                              float* __restrict__ wgt,
                                              int* __restrict__ counts,
                                              int* __restrict__ startp,
                                              int* __restrict__ nmt) {
  __shared__ int sc[NE], scur[NE];
  int t = threadIdx.x;
  if (t < NE) sc[t] = 0;
  __syncthreads();
  for (int s = t; s < NSLOTP; s += 256) tok[s] = -1;
  for (int s = t; s < NSLOT; s += 256) atomicAdd(&sc[e_sel[s]], 1);
  __syncthreads();
  if (t == 0) {
    int run = 0;
    for (int e = 0; e < NE; ++e) {
      startp[e] = run; scur[e] = run;
      counts[e] = sc[e];
      int nm = (sc[e] + 127) >> 7;   // 128-row tiles
      nmt[e] = nm;
      run += nm << 7;
    }
  }
  __syncthreads();
  for (int s = t; s < NSLOT; s += 256) {
    int e = e_sel[s];
    int pos = atomicAdd(&scur[e], 1);
    tok[pos] = s & (NTOK - 1);
    wgt[pos] = w_sel[s];
  }
}

// ---------------------------------------------------------------------------
// Gather + convert: xg[NSLOTP][DD] bf16, granule-swizzled per 128B block,
// padded rows (tok==-1) zeroed. One block per routed slot.
// ---------------------------------------------------------------------------
__global__ __launch_bounds__(256) void kgather(const float* __restrict__ x,
                                               const int* __restrict__ tok,
                                               unsigned short* __restrict__ xg) {
  int row = blockIdx.x;
  int tid = threadIdx.x;
  int t = tok[row];
  int g = tid >> 1, h = tid & 1;           // granule 0..127, half 0..1
  int b = g >> 3, gb = g & 7;
  int pos = b * 8 + (gb ^ (row & 7));
  char* dst = (char*)xg + (size_t)row * 2048 + pos * 16 + h * 8;
  short4v v = {0, 0, 0, 0};
  if (t >= 0) {
    float4 f = *(const float4*)(x + (size_t)t * DD + g * 8 + h * 4);
    v[0] = (short)f2bf(f.x); v[1] = (short)f2bf(f.y);
    v[2] = (short)f2bf(f.z); v[3] = (short)f2bf(f.w);
  }
  *(short4v*)dst = v;
}

// ---------------------------------------------------------------------------
// GEMM1+3 fused: h = silu(X@w1)*(X@w3). BM=128 BN=128 BK=64, 4 waves (2x2),
// wave-tile 64x64, all staging via global_load_lds (A from xg, B from
// pre-transposed pre-swizzled weights). h written bf16 pre-swizzled to hws.
// ---------------------------------------------------------------------------
__global__ __launch_bounds__(256) void kgemm13(
    const unsigned short* __restrict__ xg, const unsigned short* __restrict__ w1t,
    const unsigned short* __restrict__ w3t, unsigned short* __restrict__ hws,
    const int* __restrict__ counts, const int* __restrict__ startp,
    const int* __restrict__ nmt) {
  __shared__ __align__(16) char smem[48 * 1024];
  char* As = smem;                // 128 x 128B
  char* B1s = smem + 16 * 1024;   // 128 x 128B
  char* B3s = smem + 32 * 1024;   // 128 x 128B
  int e = blockIdx.z, mt = blockIdx.y;
  if (mt >= nmt[e]) return;
  int nt = blockIdx.x, n0 = nt * 128;
  int abase = startp[e] + mt * 128;
  int tid = threadIdx.x, lane = tid & 63, w = tid >> 6;
  int wm = w & 1, wn = w >> 1;
  int lr = lane >> 3, lg = lane & 7;
  const char* xgb = (const char*)xg;
  const char* w1b = (const char*)w1t + (size_t)e * HH * DD * 2;
  const char* w3b = (const char*)w3t + (size_t)e * HH * DD * 2;
  const char* srcA[4]; const char* srcB1[4]; const char* srcB3[4];
#pragma unroll
  for (int i = 0; i < 4; ++i) {
    int ra = abase + w * 32 + i * 8 + lr;
    int rb = n0 + w * 32 + i * 8 + lr;
    srcA[i] = xgb + (size_t)ra * 2048 + lg * 16;
    srcB1[i] = w1b + (size_t)rb * 2048 + lg * 16;
    srcB3[i] = w3b + (size_t)rb * 2048 + lg * 16;
  }
  f32x4 accg[4][4], accu[4][4];
#pragma unroll
  for (int i = 0; i < 4; ++i)
#pragma unroll
    for (int j = 0; j < 4; ++j) {
      accg[i][j] = (f32x4){0.f, 0.f, 0.f, 0.f};
      accu[i][j] = (f32x4){0.f, 0.f, 0.f, 0.f};
    }
  for (int k0b = 0; k0b < DD * 2; k0b += 128) {
#pragma unroll
    for (int i = 0; i < 4; ++i) {
      GLD16(srcA[i] + k0b, As + w * 4096 + i * 1024);
      GLD16(srcB1[i] + k0b, B1s + w * 4096 + i * 1024);
      GLD16(srcB3[i] + k0b, B3s + w * 4096 + i * 1024);
    }
    __syncthreads();
#pragma unroll
    for (int ks = 0; ks < 2; ++ks) {
      int g = ks * 4 + (lane >> 4);
      short8v a[4];
#pragma unroll
      for (int mf = 0; mf < 4; ++mf) {
        int r = wm * 64 + mf * 16 + (lane & 15);
        a[mf] = *(const short8v*)(As + r * 128 + ((g ^ (r & 7)) << 4));
      }
#pragma unroll
      for (int nf = 0; nf < 4; ++nf) {
        int r = wn * 64 + nf * 16 + (lane & 15);
        int off = r * 128 + ((g ^ (r & 7)) << 4);
        short8v b1 = *(const short8v*)(B1s + off);
        short8v b3 = *(const short8v*)(B3s + off);
#pragma unroll
        for (int mf = 0; mf < 4; ++mf) {
          accg[mf][nf] = __builtin_amdgcn_mfma_f32_16x16x32_bf16(
              a[mf], b1, accg[mf][nf], 0, 0, 0);
          accu[mf][nf] = __builtin_amdgcn_mfma_f32_16x16x32_bf16(
              a[mf], b3, accu[mf][nf], 0, 0, 0);
        }
      }
    }
    __syncthreads();
  }
  // Epilogue: silu(g)*u -> bf16 -> LDS restage -> swizzled coalesced store.
  unsigned short* hl = (unsigned short*)smem;  // 128 x 128 bf16 (32KB)
#pragma unroll
  for (int mf = 0; mf < 4; ++mf)
#pragma unroll
    for (int nf = 0; nf < 4; ++nf)
#pragma unroll
      for (int rr = 0; rr < 4; ++rr) {
        int row = wm * 64 + mf * 16 + (lane >> 4) * 4 + rr;
        int col = wn * 64 + nf * 16 + (lane & 15);
        float gv = accg[mf][nf][rr], uv = accu[mf][nf][rr];
        float hv = (gv / (1.f + __expf(-gv))) * uv;
        hl[row * 128 + col] = f2bf(hv);
      }
  __syncthreads();
#pragma unroll
  for (int p = 0; p < 8; ++p) {
    int idx = p * 256 + tid;
    int row = idx >> 4, g = idx & 15;
    int dp = abase + row;
    size_t db = (size_t)dp * (HH * 2) + (size_t)n0 * 2 +
                (((g & 8) | ((g & 7) ^ (dp & 7))) << 4);
    *(short8v*)((char*)hws + db) =
        *(const short8v*)((const char*)hl + row * 256 + (g << 4));
  }
}

// ---------------------------------------------------------------------------
// GEMM2: y = h @ w2, *routing weight, atomic scatter into out.
// BM=64 BN=128 BK=64, 4 waves (2x2), wave-tile 32x64, global_load_lds staging.
// ---------------------------------------------------------------------------
__global__ __launch_bounds__(256) void kgemm2(
    const unsigned short* __restrict__ hws, const unsigned short* __restrict__ w2t,
    float* __restrict__ out, const int* __restrict__ tok,
    const float* __restrict__ wgt, const int* __restrict__ counts,
    const int* __restrict__ startp, const int* __restrict__ nmt) {
  __shared__ __align__(16) char smem[24 * 1024];
  char* As = smem;               // 64 x 128B
  char* Bs = smem + 8 * 1024;    // 128 x 128B
  int e = blockIdx.z, mt = blockIdx.y;
  if (mt * 64 >= counts[e]) return;
  int nt = blockIdx.x, n0 = nt * 128;
  int mbase = startp[e] + mt * 64;
  int rem = counts[e] - mt * 64;
  int tid = threadIdx.x, lane = tid & 63, w = tid >> 6;
  int wm = w & 1, wn = w >> 1;
  int lr = lane >> 3, lg = lane & 7;
  const char* hb = (const char*)hws;
  const char* w2b = (const char*)w2t + (size_t)e * DD * HH * 2;
  const char* srcA[2]; const char* srcB[4];
#pragma unroll
  for (int i = 0; i < 2; ++i) {
    int ra = mbase + w * 16 + i * 8 + lr;
    srcA[i] = hb + (size_t)ra * (HH * 2) + lg * 16;
  }
#pragma unroll
  for (int i = 0; i < 4; ++i) {
    int rb = n0 + w * 32 + i * 8 + lr;
    srcB[i] = w2b + (size_t)rb * (HH * 2) + lg * 16;
  }
  f32x4 acc[2][4];
#pragma unroll
  for (int i = 0; i < 2; ++i)
#pragma unroll
    for (int j = 0; j < 4; ++j) acc[i][j] = (f32x4){0.f, 0.f, 0.f, 0.f};
  for (int k0b = 0; k0b < HH * 2; k0b += 128) {
#pragma unroll
    for (int i = 0; i < 2; ++i) GLD16(srcA[i] + k0b, As + w * 2048 + i * 1024);
#pragma unroll
    for (int i = 0; i < 4; ++i) GLD16(srcB[i] + k0b, Bs + w * 4096 + i * 1024);
    __syncthreads();
#pragma unroll
    for (int ks = 0; ks < 2; ++ks) {
      int g = ks * 4 + (lane >> 4);
      short8v a[2];
#pragma unroll
      for (int mf = 0; mf < 2; ++mf) {
        int r = wm * 32 + mf * 16 + (lane & 15);
        a[mf] = *(const short8v*)(As + r * 128 + ((g ^ (r & 7)) << 4));
      }
#pragma unroll
      for (int nf = 0; nf < 4; ++nf) {
        int r = wn * 64 + nf * 16 + (lane & 15);
        short8v b = *(const short8v*)(Bs + r * 128 + ((g ^ (r & 7)) << 4));
#pragma unroll
        for (int mf = 0; mf < 2; ++mf)
          acc[mf][nf] = __builtin_amdgcn_mfma_f32_16x16x32_bf16(
              a[mf], b, acc[mf][nf], 0, 0, 0);
      }
    }
    __syncthreads();
  }
#pragma unroll
  for (int mf = 0; mf < 2; ++mf)
#pragma unroll
    for (int rr = 0; rr < 4; ++rr) {
      int row = wm * 32 + mf * 16 + (lane >> 4) * 4 + rr;
      if (row < rem) {
        int t = tok[mbase + row];
        float wt = wgt[mbase + row];
        float* orow = out + (size_t)t * DD + n0;
#pragma unroll
        for (int nf = 0; nf < 4; ++nf) {
          int col = wn * 64 + nf * 16 + (lane & 15);
          atomicAdd(orow + col, wt * acc[mf][nf][rr]);
        }
      }
    }
}

// ---------------------------------------------------------------------------
extern "C" void kernel_launch(void* const* d_in, const int* in_sizes, int n_in,
                              void* d_out, int out_size, void* d_ws, size_t ws_size,
                              hipStream_t stream) {
  const float* x  = (const float*)d_in[0];
  const float* gw = (const float*)d_in[1];
  const float* w1 = (const float*)d_in[2];
  const float* w2 = (const float*)d_in[3];
  const float* w3 = (const float*)d_in[4];
  float* out = (float*)d_out;
  char* ws = (char*)d_ws;
  const size_t MB = 1024 * 1024;
  if (ws_size < 83 * MB) return;

  unsigned short* W1t = (unsigned short*)(ws);            // 32MB
  unsigned short* W3t = (unsigned short*)(ws + 32 * MB);  // 32MB
  unsigned short* W2t = (unsigned short*)(ws);            // reuse after gemm13
  unsigned short* xg  = (unsigned short*)(ws + 64 * MB);  // 6MB
  unsigned short* hws = (unsigned short*)(ws + 70 * MB);  // 12MB
  char* meta = ws + 82 * MB;
  int*   e_sel  = (int*)meta;                       // 2048
  float* w_sel  = (float*)(meta + 8192);            // 2048
  int*   tok    = (int*)(meta + 16384);             // 3072
  float* wgt    = (float*)(meta + 16384 + 12288);   // 3072
  int*   counts = (int*)(meta + 16384 + 24576);
  int*   startp = counts + 8;
  int*   nmt    = counts + 16;

  hipMemsetAsync(out, 0, (size_t)out_size * sizeof(float), stream);
  ktranspose<<<dim3(32, 16, 8), 256, 0, stream>>>(w1, W1t, DD, HH);
  ktranspose<<<dim3(32, 16, 8), 256, 0, stream>>>(w3, W3t, DD, HH);
  krouter<<<dim3(NTOK), 64, 0, stream>>>(x, gw, e_sel, w_sel);
  kbuild<<<1, 256, 0, stream>>>(e_sel, w_sel, tok, wgt, counts, startp, nmt);
  kgather<<<dim3(NSLOTP), 256, 0, stream>>>(x, tok, xg);
  kgemm13<<<dim3(16, 16, 8), 256, 0, stream>>>(xg, W1t, W3t, hws, counts,
                                               startp, nmt);
  ktranspose<<<dim3(16, 32, 8), 256, 0, stream>>>(w2, W2t, HH, DD);
  kgemm2<<<dim3(8, 32, 8), 256, 0, stream>>>(hws, W2t, out, tok, wgt, counts,
                                             startp, nmt);
}